// Round 17
// baseline (119.863 us; speedup 1.0000x reference)
//
#include <hip/hip_runtime.h>
#include <math.h>

static constexpr int kN = 8192;
static constexpr int kC = 128;
static constexpr int kB = 16;
static constexpr float kScale = 0.5f / 1048576.0f; // 1/(C*N) * 0.5 (pack fold)

#define C8  0.70710678118654752f
#define CP8 0.92387953251128676f
#define SP8 0.38268343236508977f

typedef float v2f __attribute__((ext_vector_type(2)));

__device__ __forceinline__ v2f mk2(float x, float y){ v2f r; r.x=x; r.y=y; return r; }
__device__ __forceinline__ v2f imul(v2f a){ return mk2(-a.y, a.x); }   // +i*a
__device__ __forceinline__ v2f mimul(v2f a){ return mk2(a.y, -a.x); }  // -i*a
__device__ __forceinline__ v2f cconj(v2f a){ return mk2(a.x, -a.y); }
__device__ __forceinline__ v2f cmul(v2f a, v2f b){
    return mk2(a.x*b.x - a.y*b.y, a.x*b.y + a.y*b.x);
}

// e^{+2pi i rev} via HW trans pipe (v_sin/v_cos take REVOLUTIONS).
__device__ __forceinline__ v2f wrev(float rev){
    return mk2(__builtin_amdgcn_cosf(rev), __builtin_amdgcn_sinf(rev));
}

// swizzle (validated r8): conflict-floor for stride-256 / mixed / stride-16.
__device__ __forceinline__ int swz(int n){ return n ^ ((n>>4)&15); }

// slot s = 4j+m holds A[4m+j]; A[k] lives at reg REV(k)
#define REV(k) ((((k)&3)<<2)|((k)>>2))

template<int SGN>
__device__ __forceinline__ void dft4(v2f&a, v2f&b, v2f&c, v2f&d){
    v2f t0=a+c, t1=a-c, t2=b+d, t3=b-d;
    v2f j3 = (SGN>0) ? imul(t3) : mimul(t3);
    a = t0+t2; b = t1+j3; c = t0-t2; d = t1-j3;
}

// 16-pt DFT, A_k = sum_j in[j] e^{SGN*2pi i jk/16}; in natural, out via REV.
template<int SGN>
__device__ __forceinline__ void dft16(v2f* v){
    dft4<SGN>(v[0], v[4], v[8],  v[12]);
    dft4<SGN>(v[1], v[5], v[9],  v[13]);
    dft4<SGN>(v[2], v[6], v[10], v[14]);
    dft4<SGN>(v[3], v[7], v[11], v[15]);
    const float sg = (SGN>0)? 1.f : -1.f;
    const v2f W1 = mk2(CP8,  sg*SP8);
    const v2f W2 = mk2(C8,   sg*C8);
    const v2f W3 = mk2(SP8,  sg*CP8);
    const v2f W6 = mk2(-C8,  sg*C8);
    const v2f W9 = mk2(-CP8, -sg*SP8);
    v[5]  = cmul(v[5],  W1);
    v[9]  = cmul(v[9],  W2);
    v[13] = cmul(v[13], W3);
    v[6]  = cmul(v[6],  W2);
    v[10] = (SGN>0)? imul(v[10]) : mimul(v[10]);
    v[14] = cmul(v[14], W6);
    v[7]  = cmul(v[7],  W3);
    v[11] = cmul(v[11], W6);
    v[15] = cmul(v[15], W9);
    dft4<SGN>(v[0],  v[1],  v[2],  v[3]);
    dft4<SGN>(v[4],  v[5],  v[6],  v[7]);
    dft4<SGN>(v[8],  v[9],  v[10], v[11]);
    dft4<SGN>(v[12], v[13], v[14], v[15]);
}

// DIF stage twiddle: A[m] (at reg REV(m)) *= w1^m, m=1..15
__device__ __forceinline__ void twid_dif(v2f* v, v2f w1){
    v2f w2=cmul(w1,w1), w3=cmul(w2,w1), w4=cmul(w2,w2);
    v2f w5=cmul(w2,w3), w6=cmul(w3,w3), w7=cmul(w3,w4), w8=cmul(w4,w4);
    v2f w9=cmul(w4,w5), w10=cmul(w5,w5), w11=cmul(w5,w6), w12=cmul(w6,w6);
    v2f w13=cmul(w6,w7), w14=cmul(w7,w7), w15=cmul(w7,w8);
    v[4] =cmul(v[4], w1);  v[8] =cmul(v[8], w2);  v[12]=cmul(v[12],w3);
    v[1] =cmul(v[1], w4);  v[5] =cmul(v[5], w5);  v[9] =cmul(v[9], w6);
    v[13]=cmul(v[13],w7);  v[2] =cmul(v[2], w8);  v[6] =cmul(v[6], w9);
    v[10]=cmul(v[10],w10); v[14]=cmul(v[14],w11); v[3] =cmul(v[3], w12);
    v[7] =cmul(v[7], w13); v[11]=cmul(v[11],w14); v[15]=cmul(v[15],w15);
}
// DIT stage twiddle (before dft): v[j] *= w1^j, natural index
__device__ __forceinline__ void twid_dit(v2f* v, v2f w1){
    v2f w2=cmul(w1,w1), w3=cmul(w2,w1), w4=cmul(w2,w2);
    v2f w5=cmul(w2,w3), w6=cmul(w3,w3), w7=cmul(w3,w4), w8=cmul(w4,w4);
    v2f w9=cmul(w4,w5), w10=cmul(w5,w5), w11=cmul(w5,w6), w12=cmul(w6,w6);
    v2f w13=cmul(w6,w7), w14=cmul(w7,w7), w15=cmul(w7,w8);
    v[1] =cmul(v[1], w1);  v[2] =cmul(v[2], w2);  v[3] =cmul(v[3], w3);
    v[4] =cmul(v[4], w4);  v[5] =cmul(v[5], w5);  v[6] =cmul(v[6], w6);
    v[7] =cmul(v[7], w7);  v[8] =cmul(v[8], w8);  v[9] =cmul(v[9], w9);
    v[10]=cmul(v[10],w10); v[11]=cmul(v[11],w11); v[12]=cmul(v[12],w12);
    v[13]=cmul(v[13],w13); v[14]=cmul(v[14],w14); v[15]=cmul(v[15],w15);
}

// tanh-form GELU on both components
__device__ __forceinline__ v2f gelu2(v2f v){
    v2f z = v * (0.7978845608028654f + 0.0356774081363001f * v * v);
    float e0 = __builtin_amdgcn_exp2f(-2.8853900817779268f * z.x);
    float e1 = __builtin_amdgcn_exp2f(-2.8853900817779268f * z.y);
    return mk2(v.x / (1.0f + e0), v.y / (1.0f + e1));
}

// e^{+i pi j/16}, j=0..15 (compile-time constants for the pre-combine factor)
#define WJ(j) ( (j)==0 ? mk2(1.f,0.f) : \
  (j)==1  ? mk2( 0.98078528f, 0.19509032f) : \
  (j)==2  ? mk2( 0.92387953f, 0.38268343f) : \
  (j)==3  ? mk2( 0.83146961f, 0.55557023f) : \
  (j)==4  ? mk2( 0.70710678f, 0.70710678f) : \
  (j)==5  ? mk2( 0.55557023f, 0.83146961f) : \
  (j)==6  ? mk2( 0.38268343f, 0.92387953f) : \
  (j)==7  ? mk2( 0.19509032f, 0.98078528f) : \
  (j)==8  ? mk2( 0.f,         1.f        ) : \
  (j)==9  ? mk2(-0.19509032f, 0.98078528f) : \
  (j)==10 ? mk2(-0.38268343f, 0.92387953f) : \
  (j)==11 ? mk2(-0.55557023f, 0.83146961f) : \
  (j)==12 ? mk2(-0.70710678f, 0.70710678f) : \
  (j)==13 ? mk2(-0.83146961f, 0.55557023f) : \
  (j)==14 ? mk2(-0.92387953f, 0.38268343f) : \
            mk2(-0.98078528f, 0.19509032f) )

// Kernel 1: r16 structure (Parseval stats, 2 full barriers, wave-local middle)
// + (a) pre-combine trig factored: e^{i pi k/4096} = wrev(p/8192)*WJ(j)
//   (32 trans -> 2 trans + 16 cmul per thread),
// + (b) setprio(1) around dft16/twiddle clusters (independent-WG phase overlap),
// + (c) XCD-affinity blockIdx decode (batch b -> XCD b&7, pairs with k2).
__global__ __launch_bounds__(256, 4) void k1_row(
    const float* __restrict__ xr, const float* __restrict__ xi,
    const float* __restrict__ gamma, const float* __restrict__ beta,
    float* __restrict__ outR, float* __restrict__ outI)
{
    __shared__ v2f buf[4096];   // 32 KiB, swizzled
    __shared__ v2f Twb[16];     // W256^q (stage B/B')
    __shared__ float sred[4];   // per-wave Parseval partials

    const int p    = threadIdx.x;       // 0..255
    // XCD-affinity decode: batch b lands on XCD b&7 (blockIdx%8 round-robin)
    const int bx   = blockIdx.x;
    const int rest = bx >> 3;
    const int bch  = (bx & 7) | ((rest >> 7) << 3);   // batch 0..15
    const int ch   = rest & 127;                       // channel 0..127
    const int row  = (bch << 7) | ch;

    if (p < 16) Twb[p] = wrev((float)p * (1.0f/256.0f));
    const int i0 = ((p>>4)<<8) + (p&15);  // stage-B group base

    v2f v[16];

    const float* rR = xr + (size_t)row * kN;
    const float* rI = xi + (size_t)row * kN;

    const float mean = 2.0f * rR[0];      // Sum x / N = H~[0] = 2*Re X[0]

    // ---- pre-combine (0.5 dropped; instnorm absorbs): 2*Z[k] + Parseval ----
    const v2f wp = wrev((float)p * (1.0f/8192.0f));   // e^{+i pi p/4096}
    float pq = 0.f;
    #pragma unroll
    for (int j = 0; j < 16; ++j) {
        int k   = p + (j<<8);
        int km  = (kN - k) & (kN-1);
        int km2 = 4096 - k;
        v2f w = cmul(wp, WJ(j));                       // e^{+i pi k/4096}
        v2f Hk  = mk2(rR[k]+rR[km],       rI[k]-rI[km]);
        v2f Hk2 = mk2(rR[k+4096]+rR[km2], rI[k+4096]-rI[km2]);
        pq += Hk.x*Hk.x + Hk.y*Hk.y + Hk2.x*Hk2.x + Hk2.y*Hk2.y;
        v2f S = Hk + Hk2, D = Hk - Hk2;
        v2f P = cmul(D, w);
        v[j] = S + imul(P);
    }
    // wave-reduce Parseval partial; leader writes its slot (pre-barrier)
    #pragma unroll
    for (int off = 32; off >= 1; off >>= 1)
        pq += __shfl_down(pq, off);
    if ((p & 63) == 0) sred[p>>6] = pq;

    // ---- DIF stage A (h=256), sigma=+1; w1 = W4096^p via trans pipe ----
    __builtin_amdgcn_s_setprio(1);
    dft16<1>(v);
    twid_dif(v, wrev((float)p * (1.0f/4096.0f)));
    __builtin_amdgcn_s_setprio(0);
    #pragma unroll
    for (int m = 0; m < 16; ++m) buf[swz(p + (m<<8))] = v[REV(m)];
    __syncthreads();                      // FULL (1): A->B + Twb + sred ready

    // ---- stats final (hoisted; E[x^2] = Parseval total) ----
    float total = sred[0] + sred[1] + sred[2] + sred[3];
    float var  = total - mean*mean;
    float gg = gamma[ch] * rsqrtf(var + 1e-5f);
    float bb = beta[ch] - mean * gg;

    // ==== wave-local region: B | C | norm | C' | B' ====
    const v2f wB = Twb[p & 15];
    #pragma unroll
    for (int j = 0; j < 16; ++j) v[j] = buf[swz(i0 + (j<<4))];
    __builtin_amdgcn_s_setprio(1);
    dft16<1>(v);
    twid_dif(v, wB);
    __builtin_amdgcn_s_setprio(0);
    #pragma unroll
    for (int m = 0; m < 16; ++m) buf[swz(i0 + (m<<4))] = v[REV(m)];
    __builtin_amdgcn_wave_barrier();      // B -> C (wave-local)

    #pragma unroll
    for (int j = 0; j < 16; ++j) v[j] = buf[swz((p<<4) + j)];
    __builtin_amdgcn_s_setprio(1);
    dft16<1>(v);
    // instnorm + GELU (order-agnostic), straight-line
    #pragma unroll
    for (int j = 0; j < 16; ++j) v[j] = gelu2(v[j] * gg + bb);
    // DIT stage C' (h=1): sample at slot 16p+j is v[REV(j)]
    {
        v2f u[16];
        #pragma unroll
        for (int j = 0; j < 16; ++j) u[j] = v[REV(j)];
        dft16<-1>(u);
        __builtin_amdgcn_s_setprio(0);
        #pragma unroll
        for (int m = 0; m < 16; ++m) buf[swz((p<<4) + m)] = u[REV(m)];
    }
    __builtin_amdgcn_wave_barrier();      // C' -> B' (wave-local)

    #pragma unroll
    for (int j = 0; j < 16; ++j) v[j] = buf[swz(i0 + (j<<4))];
    __builtin_amdgcn_s_setprio(1);
    twid_dit(v, cconj(wB));
    dft16<-1>(v);
    __builtin_amdgcn_s_setprio(0);
    #pragma unroll
    for (int m = 0; m < 16; ++m) buf[swz(i0 + (m<<4))] = v[REV(m)];
    __syncthreads();                      // FULL (2): B' -> A'

    // ---- DIT stage A': Z'[p+256m] at reg REV(m), straight to global ----
    #pragma unroll
    for (int j = 0; j < 16; ++j) v[j] = buf[swz(p + (j<<8))];
    __builtin_amdgcn_s_setprio(1);
    twid_dit(v, cconj(wrev((float)p * (1.0f/4096.0f))));
    dft16<-1>(v);
    __builtin_amdgcn_s_setprio(0);
    float* oR = outR + (size_t)row * kN;
    float* oI = outI + (size_t)row * kN;
    #pragma unroll
    for (int m = 0; m < 16; ++m) {
        int k = p + (m<<8);
        oR[k] = v[REV(m)].x;
        oI[k] = v[REV(m)].y;
    }
}

// Kernel 2 (r14/r15 structure, ~33 us): per (b, 32-wide colA tile): read Z'
// pair tiles (both contiguous -> full lines), build 2*Y[colA] into LDS and
// 2*Y[4096-colA] into 16 regs, two FFT passes, scale + mirror writes.
// Grid (520,2) with XCD-affinity decode: batch b -> XCD b&7, matching k1's
// writers so Z' reads can hit that XCD's L2 (falls back to L3 otherwise).
__global__ __launch_bounds__(256, 2) void k2_col(float* __restrict__ outR,
                                                 float* __restrict__ outI)
{
    __shared__ v2f tile[kC][32];  // 32 KiB
    __shared__ v2f tw[64];

    const int tid  = threadIdx.x;
    const int j    = tid & 31;
    const int g    = tid >> 5;        // 0..7
    const int gx   = blockIdx.x;      // 0..519
    const int b    = (gx & 7) | (blockIdx.y << 3);   // batch 0..15 -> XCD b&7
    const int k0   = (gx >> 3) << 5;  // 0,32,...,2048 (65 tiles)
    const int colA = k0 + j;
    const bool valid = (colA <= 2048);
    const int colB = (4096 - colA) & 4095;

    if (tid < 64) {
        tw[tid] = mk2(__builtin_amdgcn_cosf((float)tid * (1.0f/128.0f)),
                      -__builtin_amdgcn_sinf((float)tid * (1.0f/128.0f)));
    }
    const float wc =  __builtin_amdgcn_cosf((float)colA * (1.0f/8192.0f));
    const float ws = -__builtin_amdgcn_sinf((float)colA * (1.0f/8192.0f));

    float* baseR = outR + (size_t)b * kC * kN;
    float* baseI = outI + (size_t)b * kC * kN;

    v2f yb[16];   // statically indexed (unrolled) -> registers
    #pragma unroll
    for (int ci = 0; ci < 16; ++ci) {
        const int c = g + (ci << 3);
        v2f YA = mk2(0.f, 0.f), YB = mk2(0.f, 0.f);
        if (valid) {
            size_t offA = (size_t)c * kN + colA;
            size_t offB = (size_t)c * kN + colB;
            float Zx  = baseR[offA], Zy  = baseI[offA];
            float Zmx = baseR[offB], Zmy = baseI[offB];
            float Sx = Zx + Zmx, Sy = Zy - Zmy;
            float Dx = Zx - Zmx, Dy = Zy + Zmy;
            float Px = Dx*wc - Dy*ws, Py = Dx*ws + Dy*wc;
            YA = mk2(Sx + Py,  Sy - Px);   // 2*Y[colA]
            YB = mk2(Sx - Py, -Sy - Px);   // 2*Y[4096-colA]
        }
        tile[c][j] = YA;
        yb[ci] = YB;
    }
    __syncthreads();

    // ---- FFT pass A: 128-pt forward DIF along c ----
    for (int st = 7; st >= 1; --st) {
        const int h = 1 << (st-1);
        #pragma unroll
        for (int s = 0; s < 8; ++s) {
            int q   = g + (s<<3);
            int pos = q & (h-1);
            int i0  = ((q >> (st-1)) << st) + pos;
            int i1  = i0 + h;
            v2f a = tile[i0][j], bb = tile[i1][j];
            v2f w = tw[pos << (7-st)];
            tile[i0][j] = a + bb;
            tile[i1][j] = cmul(a - bb, w);
        }
        __syncthreads();
    }
    if (valid) {
        for (int p = g; p < kC; p += 8) {
            int f = (int)(__brev((unsigned)p) >> 25);
            v2f vv = tile[p][j] * kScale;
            size_t off = (size_t)f * kN + colA;
            if (colA == 0) {
                baseR[off] = vv.x; baseI[off] = 0.f;
            } else {
                baseR[off] = vv.x; baseI[off] = vv.y;
                size_t offm = (size_t)f * kN + (kN - colA);
                baseR[offm] = vv.x; baseI[offm] = -vv.y;
            }
        }
    }
    __syncthreads();   // pass-A tile reads done before overwrite

    #pragma unroll
    for (int ci = 0; ci < 16; ++ci) {
        const int c = g + (ci << 3);
        tile[c][j] = yb[ci];
    }
    __syncthreads();

    // ---- FFT pass B ----
    for (int st = 7; st >= 1; --st) {
        const int h = 1 << (st-1);
        #pragma unroll
        for (int s = 0; s < 8; ++s) {
            int q   = g + (s<<3);
            int pos = q & (h-1);
            int i0  = ((q >> (st-1)) << st) + pos;
            int i1  = i0 + h;
            v2f a = tile[i0][j], bb = tile[i1][j];
            v2f w = tw[pos << (7-st)];
            tile[i0][j] = a + bb;
            tile[i1][j] = cmul(a - bb, w);
        }
        __syncthreads();
    }
    if (valid) {
        const int kkB = 4096 - colA;
        for (int p = g; p < kC; p += 8) {
            int f = (int)(__brev((unsigned)p) >> 25);
            v2f vv = tile[p][j] * kScale;
            size_t off = (size_t)f * kN + kkB;
            if (kkB == 4096) {
                baseR[off] = vv.x; baseI[off] = 0.f;
            } else {
                baseR[off] = vv.x; baseI[off] = vv.y;
                size_t offm = (size_t)f * kN + (kN - kkB);
                baseR[offm] = vv.x; baseI[offm] = -vv.y;
            }
        }
    }
}

extern "C" void kernel_launch(void* const* d_in, const int* in_sizes, int n_in,
                              void* d_out, int out_size, void* d_ws, size_t ws_size,
                              hipStream_t stream)
{
    const float* xr    = (const float*)d_in[0];
    const float* xi    = (const float*)d_in[1];
    const float* gamma = (const float*)d_in[2];
    const float* beta  = (const float*)d_in[3];

    float* outR = (float*)d_out;
    float* outI = outR + (size_t)kB * kC * kN;

    k1_row<<<kB * kC, 256, 0, stream>>>(xr, xi, gamma, beta, outR, outI);
    k2_col<<<dim3(520, 2), 256, 0, stream>>>(outR, outI);
}

// Round 18
// 107.318 us; speedup vs baseline: 1.1169x; 1.1169x over previous
//
#include <hip/hip_runtime.h>
#include <math.h>

static constexpr int kN = 8192;
static constexpr int kC = 128;
static constexpr int kB = 16;
static constexpr float kScale = 0.5f / 1048576.0f; // 1/(C*N) * 0.5 (pack fold)

#define C8  0.70710678118654752f
#define CP8 0.92387953251128676f
#define SP8 0.38268343236508977f

typedef float v2f __attribute__((ext_vector_type(2)));

__device__ __forceinline__ v2f mk2(float x, float y){ v2f r; r.x=x; r.y=y; return r; }
__device__ __forceinline__ v2f imul(v2f a){ return mk2(-a.y, a.x); }   // +i*a
__device__ __forceinline__ v2f mimul(v2f a){ return mk2(a.y, -a.x); }  // -i*a
__device__ __forceinline__ v2f cconj(v2f a){ return mk2(a.x, -a.y); }
__device__ __forceinline__ v2f cmul(v2f a, v2f b){
    return mk2(a.x*b.x - a.y*b.y, a.x*b.y + a.y*b.x);
}

// e^{+2pi i rev} via HW trans pipe (v_sin/v_cos take REVOLUTIONS).
__device__ __forceinline__ v2f wrev(float rev){
    return mk2(__builtin_amdgcn_cosf(rev), __builtin_amdgcn_sinf(rev));
}

// swizzle (validated r8): conflict-floor for stride-256 / mixed / stride-16.
// Permutes only within each 256-block -> preserves 1024-block wave-locality.
__device__ __forceinline__ int swz(int n){ return n ^ ((n>>4)&15); }

// slot s = 4j+m holds A[4m+j]; A[k] lives at reg REV(k)
#define REV(k) ((((k)&3)<<2)|((k)>>2))

template<int SGN>
__device__ __forceinline__ void dft4(v2f&a, v2f&b, v2f&c, v2f&d){
    v2f t0=a+c, t1=a-c, t2=b+d, t3=b-d;
    v2f j3 = (SGN>0) ? imul(t3) : mimul(t3);
    a = t0+t2; b = t1+j3; c = t0-t2; d = t1-j3;
}

// 16-pt DFT, A_k = sum_j in[j] e^{SGN*2pi i jk/16}; in natural, out via REV.
template<int SGN>
__device__ __forceinline__ void dft16(v2f* v){
    dft4<SGN>(v[0], v[4], v[8],  v[12]);
    dft4<SGN>(v[1], v[5], v[9],  v[13]);
    dft4<SGN>(v[2], v[6], v[10], v[14]);
    dft4<SGN>(v[3], v[7], v[11], v[15]);
    const float sg = (SGN>0)? 1.f : -1.f;
    const v2f W1 = mk2(CP8,  sg*SP8);
    const v2f W2 = mk2(C8,   sg*C8);
    const v2f W3 = mk2(SP8,  sg*CP8);
    const v2f W6 = mk2(-C8,  sg*C8);
    const v2f W9 = mk2(-CP8, -sg*SP8);
    v[5]  = cmul(v[5],  W1);
    v[9]  = cmul(v[9],  W2);
    v[13] = cmul(v[13], W3);
    v[6]  = cmul(v[6],  W2);
    v[10] = (SGN>0)? imul(v[10]) : mimul(v[10]);
    v[14] = cmul(v[14], W6);
    v[7]  = cmul(v[7],  W3);
    v[11] = cmul(v[11], W6);
    v[15] = cmul(v[15], W9);
    dft4<SGN>(v[0],  v[1],  v[2],  v[3]);
    dft4<SGN>(v[4],  v[5],  v[6],  v[7]);
    dft4<SGN>(v[8],  v[9],  v[10], v[11]);
    dft4<SGN>(v[12], v[13], v[14], v[15]);
}

// DIF stage twiddle: A[m] (at reg REV(m)) *= w1^m, m=1..15
__device__ __forceinline__ void twid_dif(v2f* v, v2f w1){
    v2f w2=cmul(w1,w1), w3=cmul(w2,w1), w4=cmul(w2,w2);
    v2f w5=cmul(w2,w3), w6=cmul(w3,w3), w7=cmul(w3,w4), w8=cmul(w4,w4);
    v2f w9=cmul(w4,w5), w10=cmul(w5,w5), w11=cmul(w5,w6), w12=cmul(w6,w6);
    v2f w13=cmul(w6,w7), w14=cmul(w7,w7), w15=cmul(w7,w8);
    v[4] =cmul(v[4], w1);  v[8] =cmul(v[8], w2);  v[12]=cmul(v[12],w3);
    v[1] =cmul(v[1], w4);  v[5] =cmul(v[5], w5);  v[9] =cmul(v[9], w6);
    v[13]=cmul(v[13],w7);  v[2] =cmul(v[2], w8);  v[6] =cmul(v[6], w9);
    v[10]=cmul(v[10],w10); v[14]=cmul(v[14],w11); v[3] =cmul(v[3], w12);
    v[7] =cmul(v[7], w13); v[11]=cmul(v[11],w14); v[15]=cmul(v[15],w15);
}
// DIT stage twiddle (before dft): v[j] *= w1^j, natural index
__device__ __forceinline__ void twid_dit(v2f* v, v2f w1){
    v2f w2=cmul(w1,w1), w3=cmul(w2,w1), w4=cmul(w2,w2);
    v2f w5=cmul(w2,w3), w6=cmul(w3,w3), w7=cmul(w3,w4), w8=cmul(w4,w4);
    v2f w9=cmul(w4,w5), w10=cmul(w5,w5), w11=cmul(w5,w6), w12=cmul(w6,w6);
    v2f w13=cmul(w6,w7), w14=cmul(w7,w7), w15=cmul(w7,w8);
    v[1] =cmul(v[1], w1);  v[2] =cmul(v[2], w2);  v[3] =cmul(v[3], w3);
    v[4] =cmul(v[4], w4);  v[5] =cmul(v[5], w5);  v[6] =cmul(v[6], w6);
    v[7] =cmul(v[7], w7);  v[8] =cmul(v[8], w8);  v[9] =cmul(v[9], w9);
    v[10]=cmul(v[10],w10); v[11]=cmul(v[11],w11); v[12]=cmul(v[12],w12);
    v[13]=cmul(v[13],w13); v[14]=cmul(v[14],w14); v[15]=cmul(v[15],w15);
}

// tanh-form GELU on both components
__device__ __forceinline__ v2f gelu2(v2f v){
    v2f z = v * (0.7978845608028654f + 0.0356774081363001f * v * v);
    float e0 = __builtin_amdgcn_exp2f(-2.8853900817779268f * z.x);
    float e1 = __builtin_amdgcn_exp2f(-2.8853900817779268f * z.y);
    return mk2(v.x / (1.0f + e0), v.y / (1.0f + e1));
}

// Kernel 1 (r16 verbatim, best measured: ~73 us): radix-16^3, Parseval stats
// (mean = 2*xr[0], E[x^2] from pre-combine), 2 full barriers + wave-local
// middle, trans-pipe twiddles, 32 KiB swizzled LDS.
__global__ __launch_bounds__(256, 4) void k1_row(
    const float* __restrict__ xr, const float* __restrict__ xi,
    const float* __restrict__ gamma, const float* __restrict__ beta,
    float* __restrict__ outR, float* __restrict__ outI)
{
    __shared__ v2f buf[4096];   // 32 KiB, swizzled
    __shared__ v2f Twb[16];     // W256^q (stage B/B')
    __shared__ float sred[4];   // per-wave Parseval partials

    const int p   = threadIdx.x;        // 0..255
    const int row = blockIdx.x;
    const int ch  = row & (kC-1);

    if (p < 16) Twb[p] = wrev((float)p * (1.0f/256.0f));
    const int i0 = ((p>>4)<<8) + (p&15);  // stage-B group base

    v2f v[16];

    const float* rR = xr + (size_t)row * kN;
    const float* rI = xi + (size_t)row * kN;

    const float mean = 2.0f * rR[0];      // Sum x / N = H~[0] = 2*Re X[0]

    // ---- pre-combine (0.5 dropped; instnorm absorbs): 2*Z[k] + Parseval ----
    float pq = 0.f;
    #pragma unroll
    for (int j = 0; j < 16; ++j) {
        int k   = p + (j<<8);
        int km  = (kN - k) & (kN-1);
        int km2 = 4096 - k;
        v2f w = wrev((float)k * (1.0f/8192.0f));   // e^{+i pi k/4096}
        v2f Hk  = mk2(rR[k]+rR[km],       rI[k]-rI[km]);
        v2f Hk2 = mk2(rR[k+4096]+rR[km2], rI[k+4096]-rI[km2]);
        pq += Hk.x*Hk.x + Hk.y*Hk.y + Hk2.x*Hk2.x + Hk2.y*Hk2.y;
        v2f S = Hk + Hk2, D = Hk - Hk2;
        v2f P = cmul(D, w);
        v[j] = S + imul(P);
    }
    // wave-reduce Parseval partial; leader writes its slot (pre-barrier)
    #pragma unroll
    for (int off = 32; off >= 1; off >>= 1)
        pq += __shfl_down(pq, off);
    if ((p & 63) == 0) sred[p>>6] = pq;

    // ---- DIF stage A (h=256), sigma=+1; w1 = W4096^p via trans pipe ----
    dft16<1>(v);
    twid_dif(v, wrev((float)p * (1.0f/4096.0f)));
    #pragma unroll
    for (int m = 0; m < 16; ++m) buf[swz(p + (m<<8))] = v[REV(m)];
    __syncthreads();                      // FULL (1): A->B + Twb + sred ready

    // ---- stats final (hoisted; E[x^2] = Parseval total) ----
    float total = sred[0] + sred[1] + sred[2] + sred[3];
    float var  = total - mean*mean;
    float gg = gamma[ch] * rsqrtf(var + 1e-5f);
    float bb = beta[ch] - mean * gg;

    // ==== wave-local region: B | C | norm | C' | B' ====
    const v2f wB = Twb[p & 15];
    #pragma unroll
    for (int j = 0; j < 16; ++j) v[j] = buf[swz(i0 + (j<<4))];
    dft16<1>(v);
    twid_dif(v, wB);
    #pragma unroll
    for (int m = 0; m < 16; ++m) buf[swz(i0 + (m<<4))] = v[REV(m)];
    __builtin_amdgcn_wave_barrier();      // B -> C (wave-local)

    #pragma unroll
    for (int j = 0; j < 16; ++j) v[j] = buf[swz((p<<4) + j)];
    dft16<1>(v);

    // instnorm + GELU (order-agnostic), straight-line
    #pragma unroll
    for (int j = 0; j < 16; ++j) v[j] = gelu2(v[j] * gg + bb);

    // DIT stage C' (h=1): sample at slot 16p+j is v[REV(j)]
    {
        v2f u[16];
        #pragma unroll
        for (int j = 0; j < 16; ++j) u[j] = v[REV(j)];
        dft16<-1>(u);
        #pragma unroll
        for (int m = 0; m < 16; ++m) buf[swz((p<<4) + m)] = u[REV(m)];
    }
    __builtin_amdgcn_wave_barrier();      // C' -> B' (wave-local)

    #pragma unroll
    for (int j = 0; j < 16; ++j) v[j] = buf[swz(i0 + (j<<4))];
    twid_dit(v, cconj(wB));
    dft16<-1>(v);
    #pragma unroll
    for (int m = 0; m < 16; ++m) buf[swz(i0 + (m<<4))] = v[REV(m)];
    __syncthreads();                      // FULL (2): B' -> A'

    // ---- DIT stage A': Z'[p+256m] at reg REV(m), straight to global ----
    #pragma unroll
    for (int j = 0; j < 16; ++j) v[j] = buf[swz(p + (j<<8))];
    twid_dit(v, cconj(wrev((float)p * (1.0f/4096.0f))));
    dft16<-1>(v);
    float* oR = outR + (size_t)row * kN;
    float* oI = outI + (size_t)row * kN;
    #pragma unroll
    for (int m = 0; m < 16; ++m) {
        int k = p + (m<<8);
        oR[k] = v[REV(m)].x;
        oI[k] = v[REV(m)].y;
    }
}

// Kernel 2 (r16 verbatim, ~33 us ~= 92% of its HBM floor): per (b, 32-wide
// colA tile): read Z' pair tiles (both contiguous -> full lines), build
// 2*Y[colA] into LDS and 2*Y[4096-colA] into 16 regs, two FFT passes,
// scale + Hermitian-mirror writes in place.
__global__ __launch_bounds__(256, 2) void k2_col(float* __restrict__ outR,
                                                 float* __restrict__ outI)
{
    __shared__ v2f tile[kC][32];  // 32 KiB
    __shared__ v2f tw[64];

    const int tid  = threadIdx.x;
    const int j    = tid & 31;
    const int g    = tid >> 5;        // 0..7
    const int b    = blockIdx.y;
    const int k0   = blockIdx.x << 5; // 0,32,...,2048 (65 blocks)
    const int colA = k0 + j;
    const bool valid = (colA <= 2048);
    const int colB = (4096 - colA) & 4095;

    if (tid < 64) {
        tw[tid] = mk2(__builtin_amdgcn_cosf((float)tid * (1.0f/128.0f)),
                      -__builtin_amdgcn_sinf((float)tid * (1.0f/128.0f)));
    }
    const float wc =  __builtin_amdgcn_cosf((float)colA * (1.0f/8192.0f));
    const float ws = -__builtin_amdgcn_sinf((float)colA * (1.0f/8192.0f));

    float* baseR = outR + (size_t)b * kC * kN;
    float* baseI = outI + (size_t)b * kC * kN;

    v2f yb[16];   // statically indexed (unrolled) -> registers
    #pragma unroll
    for (int ci = 0; ci < 16; ++ci) {
        const int c = g + (ci << 3);
        v2f YA = mk2(0.f, 0.f), YB = mk2(0.f, 0.f);
        if (valid) {
            size_t offA = (size_t)c * kN + colA;
            size_t offB = (size_t)c * kN + colB;
            float Zx  = baseR[offA], Zy  = baseI[offA];
            float Zmx = baseR[offB], Zmy = baseI[offB];
            float Sx = Zx + Zmx, Sy = Zy - Zmy;
            float Dx = Zx - Zmx, Dy = Zy + Zmy;
            float Px = Dx*wc - Dy*ws, Py = Dx*ws + Dy*wc;
            YA = mk2(Sx + Py,  Sy - Px);   // 2*Y[colA]
            YB = mk2(Sx - Py, -Sy - Px);   // 2*Y[4096-colA]
        }
        tile[c][j] = YA;
        yb[ci] = YB;
    }
    __syncthreads();

    // ---- FFT pass A: 128-pt forward DIF along c ----
    for (int st = 7; st >= 1; --st) {
        const int h = 1 << (st-1);
        #pragma unroll
        for (int s = 0; s < 8; ++s) {
            int q   = g + (s<<3);
            int pos = q & (h-1);
            int i0  = ((q >> (st-1)) << st) + pos;
            int i1  = i0 + h;
            v2f a = tile[i0][j], bb = tile[i1][j];
            v2f w = tw[pos << (7-st)];
            tile[i0][j] = a + bb;
            tile[i1][j] = cmul(a - bb, w);
        }
        __syncthreads();
    }
    if (valid) {
        for (int p = g; p < kC; p += 8) {
            int f = (int)(__brev((unsigned)p) >> 25);
            v2f vv = tile[p][j] * kScale;
            size_t off = (size_t)f * kN + colA;
            if (colA == 0) {
                baseR[off] = vv.x; baseI[off] = 0.f;
            } else {
                baseR[off] = vv.x; baseI[off] = vv.y;
                size_t offm = (size_t)f * kN + (kN - colA);
                baseR[offm] = vv.x; baseI[offm] = -vv.y;
            }
        }
    }
    __syncthreads();   // pass-A tile reads done before overwrite

    #pragma unroll
    for (int ci = 0; ci < 16; ++ci) {
        const int c = g + (ci << 3);
        tile[c][j] = yb[ci];
    }
    __syncthreads();

    // ---- FFT pass B ----
    for (int st = 7; st >= 1; --st) {
        const int h = 1 << (st-1);
        #pragma unroll
        for (int s = 0; s < 8; ++s) {
            int q   = g + (s<<3);
            int pos = q & (h-1);
            int i0  = ((q >> (st-1)) << st) + pos;
            int i1  = i0 + h;
            v2f a = tile[i0][j], bb = tile[i1][j];
            v2f w = tw[pos << (7-st)];
            tile[i0][j] = a + bb;
            tile[i1][j] = cmul(a - bb, w);
        }
        __syncthreads();
    }
    if (valid) {
        const int kkB = 4096 - colA;
        for (int p = g; p < kC; p += 8) {
            int f = (int)(__brev((unsigned)p) >> 25);
            v2f vv = tile[p][j] * kScale;
            size_t off = (size_t)f * kN + kkB;
            if (kkB == 4096) {
                baseR[off] = vv.x; baseI[off] = 0.f;
            } else {
                baseR[off] = vv.x; baseI[off] = vv.y;
                size_t offm = (size_t)f * kN + (kN - kkB);
                baseR[offm] = vv.x; baseI[offm] = -vv.y;
            }
        }
    }
}

extern "C" void kernel_launch(void* const* d_in, const int* in_sizes, int n_in,
                              void* d_out, int out_size, void* d_ws, size_t ws_size,
                              hipStream_t stream)
{
    const float* xr    = (const float*)d_in[0];
    const float* xi    = (const float*)d_in[1];
    const float* gamma = (const float*)d_in[2];
    const float* beta  = (const float*)d_in[3];

    float* outR = (float*)d_out;
    float* outI = outR + (size_t)kB * kC * kN;

    k1_row<<<kB * kC, 256, 0, stream>>>(xr, xi, gamma, beta, outR, outI);
    k2_col<<<dim3(65, kB), 256, 0, stream>>>(outR, outI);
}